// Round 9
// baseline (780.747 us; speedup 1.0000x reference)
//
#include <hip/hip_runtime.h>
#include <math.h>

#define E 16
#define D 64
#define H 128
#define R 4            // n-rows per block
#define ROWS (R * E)   // 64 expert-rows per block
#define MW 16          // expert-rows per wave (spec GEMM)

// ---------------------------------------------------------------------------
// Prep: Wabc[c][j] = Wa + Wb + Wc  (spec_W1 rows 0..127, 128..255, 256..383)
// ---------------------------------------------------------------------------
__global__ void wabc_prep(const float* __restrict__ specW1, float* __restrict__ wabc) {
    int i = blockIdx.x * blockDim.x + threadIdx.x;
    if (i < H * H) {
        wabc[i] = specW1[i] + specW1[H * H + i] + specW1[2 * H * H + i];
    }
}

// ---------------------------------------------------------------------------
// Fused router. Block = 256 threads (4 waves), R=4. LDS 48.4 KB -> 3
// blocks/CU (12 waves): tokens read straight from global (no staging),
// encoder in two 32-row passes through a 16 KB h-buffer, scratch carved
// into the dead h-buffer. GEMM tiling: half-wave j4 (lane = hw, jl; one
// b128 activation read feeds 16-32 FMAs). Stage 6 computes |enc-full|
// on the fly. Per-accumulator FMA order identical to R7 (absmax 0).
// ---------------------------------------------------------------------------
template <bool USE_WABC>
__global__ __launch_bounds__(256, 3)
void router_kernel(const float* __restrict__ tokens,
                   const float* __restrict__ encW1, const float* __restrict__ encB1,
                   const float* __restrict__ encW2, const float* __restrict__ encB2,
                   const float* __restrict__ specW1, const float* __restrict__ specB1,
                   const float* __restrict__ specW2,
                   const float* __restrict__ defW1, const float* __restrict__ defB1,
                   const float* __restrict__ defW2, const float* __restrict__ defB2,
                   const int* __restrict__ fiPtr, const int* __restrict__ tkPtr,
                   const float* __restrict__ wabc,
                   float* __restrict__ out, int N) {
    __shared__ float bufA[ROWS * H];    // 32 KB: encoded
    __shared__ float bufB[32 * H];      // 16 KB: h (per pass) -> carved scratch
    __shared__ float s_logits[ROWS];
    __shared__ float s_dred[R];

    const int tid   = threadIdx.x;
    const int n0    = blockIdx.x * R;
    const int fi    = fiPtr[0];
    const int lane  = tid & 63;
    const int wq    = tid >> 6;        // wave 0..3
    const int hw    = lane >> 5;       // half-wave 0/1
    const int jl    = lane & 31;
    const int jw0   = jl * 4;          // this lane's 4-col chunk

    // ================= encoder: two passes of 32 rows =================
#pragma unroll 1
    for (int p = 0; p < 2; p++) {
        const int lr0 = wq * 8 + hw * 4;      // local row base (0..28)
        const int gr0 = p * 32 + lr0;         // block row base (0..60)
        long rowb = (long)n0 * E + gr0;       // 4 consecutive token rows
        if (rowb > (long)N * E - 4) rowb = (long)N * E - 4;  // clamp (identity when in range)
        const float* __restrict__ tb = tokens + rowb * D;

        // ---- enc1: h = relu(tok @ W1 + b1), K=64; global -> bufB ----
        {
            float acc[4][4];
#pragma unroll
            for (int m = 0; m < 4; m++)
#pragma unroll
                for (int j = 0; j < 4; j++) acc[m][j] = 0.f;
#pragma unroll 2
            for (int k = 0; k < D; k += 4) {
                float4 w0 = *(const float4*)(encW1 + (k + 0) * H + jw0);
                float4 w1 = *(const float4*)(encW1 + (k + 1) * H + jw0);
                float4 w2 = *(const float4*)(encW1 + (k + 2) * H + jw0);
                float4 w3 = *(const float4*)(encW1 + (k + 3) * H + jw0);
#pragma unroll
                for (int m = 0; m < 4; m++) {
                    float4 t = *(const float4*)(tb + m * D + k);
                    acc[m][0] = fmaf(t.w, w3.x, fmaf(t.z, w2.x, fmaf(t.y, w1.x, fmaf(t.x, w0.x, acc[m][0]))));
                    acc[m][1] = fmaf(t.w, w3.y, fmaf(t.z, w2.y, fmaf(t.y, w1.y, fmaf(t.x, w0.y, acc[m][1]))));
                    acc[m][2] = fmaf(t.w, w3.z, fmaf(t.z, w2.z, fmaf(t.y, w1.z, fmaf(t.x, w0.z, acc[m][2]))));
                    acc[m][3] = fmaf(t.w, w3.w, fmaf(t.z, w2.w, fmaf(t.y, w1.w, fmaf(t.x, w0.w, acc[m][3]))));
                }
            }
            float4 b = *(const float4*)(encB1 + jw0);
#pragma unroll
            for (int m = 0; m < 4; m++) {
                float4 o;
                o.x = fmaxf(acc[m][0] + b.x, 0.f);
                o.y = fmaxf(acc[m][1] + b.y, 0.f);
                o.z = fmaxf(acc[m][2] + b.z, 0.f);
                o.w = fmaxf(acc[m][3] + b.w, 0.f);
                *(float4*)(bufB + (lr0 + m) * H + jw0) = o;
            }
        }
        __syncthreads();

        // ---- enc2: encoded = relu(h @ W2 + b2), K=128; bufB -> bufA ----
        {
            float acc[4][4];
#pragma unroll
            for (int m = 0; m < 4; m++)
#pragma unroll
                for (int j = 0; j < 4; j++) acc[m][j] = 0.f;
#pragma unroll 2
            for (int k = 0; k < H; k += 4) {
                float4 w0 = *(const float4*)(encW2 + (k + 0) * H + jw0);
                float4 w1 = *(const float4*)(encW2 + (k + 1) * H + jw0);
                float4 w2 = *(const float4*)(encW2 + (k + 2) * H + jw0);
                float4 w3 = *(const float4*)(encW2 + (k + 3) * H + jw0);
#pragma unroll
                for (int m = 0; m < 4; m++) {
                    float4 t = *(const float4*)(bufB + (lr0 + m) * H + k);
                    acc[m][0] = fmaf(t.w, w3.x, fmaf(t.z, w2.x, fmaf(t.y, w1.x, fmaf(t.x, w0.x, acc[m][0]))));
                    acc[m][1] = fmaf(t.w, w3.y, fmaf(t.z, w2.y, fmaf(t.y, w1.y, fmaf(t.x, w0.y, acc[m][1]))));
                    acc[m][2] = fmaf(t.w, w3.z, fmaf(t.z, w2.z, fmaf(t.y, w1.z, fmaf(t.x, w0.z, acc[m][2]))));
                    acc[m][3] = fmaf(t.w, w3.w, fmaf(t.z, w2.w, fmaf(t.y, w1.w, fmaf(t.x, w0.w, acc[m][3]))));
                }
            }
            float4 b = *(const float4*)(encB2 + jw0);
#pragma unroll
            for (int m = 0; m < 4; m++) {
                float4 o;
                o.x = fmaxf(acc[m][0] + b.x, 0.f);
                o.y = fmaxf(acc[m][1] + b.y, 0.f);
                o.z = fmaxf(acc[m][2] + b.z, 0.f);
                o.w = fmaxf(acc[m][3] + b.w, 0.f);
                *(float4*)(bufA + (gr0 + m) * H + jw0) = o;
            }
        }
        __syncthreads();
    }

    // carved scratch in the now-dead bufB (4096 floats total)
    float* s_full = bufB;               // [R][H]
    float* s_glob = bufB + 512;         // [R][H]
    float* s_mabs = bufB + 1024;        // [R][H]
    float* s_bias = bufB + 1536;        // [R][H]
    float* s_pB   = bufB + 2048;        // [2][R][H]
    float* s_pD   = bufB + 3072;        // [2][R][H]

    // ---- stats: full, glob mean, mean|delta| ----
    {
        const int r4 = tid >> 6;       // 0..3
        const int cb = tid & 63;
#pragma unroll
        for (int half = 0; half < 2; half++) {
            const int c = cb + half * 64;
            const float* er = bufA + (r4 * E) * H + c;
            float v[E];
#pragma unroll
            for (int e = 0; e < E; e++) v[e] = er[e * H];
            float s = 0.f;
#pragma unroll
            for (int e = 0; e < E; e++) s += v[e];
            float fc = v[fi];
            float ma = 0.f;
#pragma unroll
            for (int e = 0; e < E; e++) ma += fabsf(v[e] - fc);
            s_full[r4 * H + c] = fc;
            s_glob[r4 * H + c] = s * (1.f / 16.f);
            s_mabs[r4 * H + c] = ma * (1.f / 16.f);
        }
    }
    __syncthreads();

    // ---- GEMV partials: bias = full@Wb + glob@Wc; def head ----
    {
        const int jp = tid & 63;       // j-pair index
        const int jj = jp * 2;
        const int kh = (tid >> 6) & 1; // K-half
        const int rg = tid >> 7;       // r-group (rows rg*2, rg*2+1)
        const int c0 = kh * 64;
        const float* __restrict__ Wb = specW1 + H * H;
        const float* __restrict__ Wc = specW1 + 2 * H * H;
        float accB[2][2] = {{0.f, 0.f}, {0.f, 0.f}};
        float accD[2][2] = {{0.f, 0.f}, {0.f, 0.f}};
        for (int cc = 0; cc < 64; cc++) {
            const int c = c0 + cc;
            float2 wb = *(const float2*)(Wb + c * H + jj);
            float2 wc = *(const float2*)(Wc + c * H + jj);
            float2 d0 = *(const float2*)(defW1 + c * H + jj);
            float2 d1 = *(const float2*)(defW1 + (H + c) * H + jj);
            float2 d2 = *(const float2*)(defW1 + (2 * H + c) * H + jj);
#pragma unroll
            for (int rl = 0; rl < 2; rl++) {
                const int r = rg * 2 + rl;
                float fv = s_full[r * H + c];
                float gv = s_glob[r * H + c];
                float mv = s_mabs[r * H + c];
                accB[rl][0] = fmaf(fv, wb.x, accB[rl][0]);
                accB[rl][1] = fmaf(fv, wb.y, accB[rl][1]);
                accB[rl][0] = fmaf(gv, wc.x, accB[rl][0]);
                accB[rl][1] = fmaf(gv, wc.y, accB[rl][1]);
                accD[rl][0] = fmaf(fv, d0.x, accD[rl][0]);
                accD[rl][1] = fmaf(fv, d0.y, accD[rl][1]);
                accD[rl][0] = fmaf(gv, d1.x, accD[rl][0]);
                accD[rl][1] = fmaf(gv, d1.y, accD[rl][1]);
                accD[rl][0] = fmaf(mv, d2.x, accD[rl][0]);
                accD[rl][1] = fmaf(mv, d2.y, accD[rl][1]);
            }
        }
#pragma unroll
        for (int rl = 0; rl < 2; rl++) {
            const int r = rg * 2 + rl;
            *(float2*)(s_pB + (kh * R + r) * H + jj) = make_float2(accB[rl][0], accB[rl][1]);
            *(float2*)(s_pD + (kh * R + r) * H + jj) = make_float2(accD[rl][0], accD[rl][1]);
        }
    }
    __syncthreads();

    // ---- finalize bias and defer logit (wave wq owns row wq) ----
    {
        float dv = 0.f;
#pragma unroll
        for (int t = 0; t < 2; t++) {
            const int j = lane + t * 64;
            float pb = s_pB[wq * H + j] + s_pB[(R + wq) * H + j];
            s_bias[wq * H + j] = specB1[j] - pb;
            float pd = defB1[j] + s_pD[wq * H + j] + s_pD[(R + wq) * H + j];
            dv += fmaxf(pd, 0.f) * defW2[j];
        }
#pragma unroll
        for (int off = 32; off; off >>= 1) dv += __shfl_xor(dv, off, 64);
        if (lane == 0) s_dred[wq] = dv;
    }
    __syncthreads();

    // ---- spec GEMM: relu(enc@Wabc + |enc-full|@Wd + bias) -> logits ----
    {
        const int mb2 = wq * MW + hw * 8;  // first of this lane's 8 rows
        float acc[8][4];
#pragma unroll
        for (int m = 0; m < 8; m++)
#pragma unroll
            for (int j = 0; j < 4; j++) acc[m][j] = 0.f;
        const float* __restrict__ Wd = specW1 + 3 * H * H;
        for (int k = 0; k < H; k += 4) {
            float4 wa0, wa1, wa2, wa3;
            if (USE_WABC) {
                wa0 = *(const float4*)(wabc + (k + 0) * H + jw0);
                wa1 = *(const float4*)(wabc + (k + 1) * H + jw0);
                wa2 = *(const float4*)(wabc + (k + 2) * H + jw0);
                wa3 = *(const float4*)(wabc + (k + 3) * H + jw0);
            } else {
#pragma unroll
                for (int t = 0; t < 4; t++) {
                    const float* p = specW1 + (k + t) * H + jw0;
                    float4 x0 = *(const float4*)(p);
                    float4 x1 = *(const float4*)(p + H * H);
                    float4 x2 = *(const float4*)(p + 2 * H * H);
                    float4 s4 = make_float4(x0.x + x1.x + x2.x, x0.y + x1.y + x2.y,
                                            x0.z + x1.z + x2.z, x0.w + x1.w + x2.w);
                    if (t == 0) wa0 = s4; else if (t == 1) wa1 = s4;
                    else if (t == 2) wa2 = s4; else wa3 = s4;
                }
            }
            float4 wd0 = *(const float4*)(Wd + (k + 0) * H + jw0);
            float4 wd1 = *(const float4*)(Wd + (k + 1) * H + jw0);
            float4 wd2 = *(const float4*)(Wd + (k + 2) * H + jw0);
            float4 wd3 = *(const float4*)(Wd + (k + 3) * H + jw0);
            float4 f4 = *(const float4*)(s_full + wq * H + k);   // uniform broadcast
#pragma unroll
            for (int m = 0; m < 8; m++) {
                float4 ev = *(const float4*)(bufA + (mb2 + m) * H + k);
                float ax = fabsf(ev.x - f4.x);
                float ay = fabsf(ev.y - f4.y);
                float az = fabsf(ev.z - f4.z);
                float aw = fabsf(ev.w - f4.w);
#pragma unroll
                for (int j = 0; j < 4; j++) {
                    const float* waj0 = &wa0.x, *waj1 = &wa1.x, *waj2 = &wa2.x, *waj3 = &wa3.x;
                    const float* wdj0 = &wd0.x, *wdj1 = &wd1.x, *wdj2 = &wd2.x, *wdj3 = &wd3.x;
                    float a = acc[m][j];
                    a = fmaf(ev.x, waj0[j], a);
                    a = fmaf(ev.y, waj1[j], a);
                    a = fmaf(ev.z, waj2[j], a);
                    a = fmaf(ev.w, waj3[j], a);
                    a = fmaf(ax, wdj0[j], a);
                    a = fmaf(ay, wdj1[j], a);
                    a = fmaf(az, wdj2[j], a);
                    a = fmaf(aw, wdj3[j], a);
                    acc[m][j] = a;
                }
            }
        }
        // epilogue: logit per row via 32-lane reduce (spec_b2 dropped)
        float4 bn = *(const float4*)(s_bias + wq * H + jw0);
        float4 w2 = *(const float4*)(specW2 + jw0);
#pragma unroll
        for (int m = 0; m < 8; m++) {
            float p = 0.f;
            p += fmaxf(acc[m][0] + bn.x, 0.f) * w2.x;
            p += fmaxf(acc[m][1] + bn.y, 0.f) * w2.y;
            p += fmaxf(acc[m][2] + bn.z, 0.f) * w2.z;
            p += fmaxf(acc[m][3] + bn.w, 0.f) * w2.w;
#pragma unroll
            for (int off = 1; off < 32; off <<= 1) p += __shfl_xor(p, off, 64);
            if (jl == 0) s_logits[mb2 + m] = p;
        }
    }
    __syncthreads();

    // ---- finalize (R threads: one per n-row) ----
    if (tid < R && (n0 + tid) < N) {
        const int r = tid;
        const int n = n0 + r;
        float s = s_dred[r] + defB2[0];
        out[(size_t)N * E + n] = 1.f / (1.f + expf(-s));
        int k = tkPtr[0];
        if (k < 1) k = 1;
        if (k > E - 1) k = E - 1;
        unsigned chosen = 0u;
        for (int kk = 0; kk < k; kk++) {
            float bv = -INFINITY;
            int bi = 0;
            for (int e = 0; e < E; e++) {
                if (e == fi || ((chosen >> e) & 1u)) continue;
                float v = s_logits[r * E + e];
                if (v > bv) { bv = v; bi = e; }
            }
            chosen |= (1u << bi);
        }
        float mx = -INFINITY;
        for (int e = 0; e < E; e++)
            if ((chosen >> e) & 1u) { float v = s_logits[r * E + e]; if (v > mx) mx = v; }
        float ssum = 0.f;
        for (int e = 0; e < E; e++)
            if ((chosen >> e) & 1u) ssum += expf(s_logits[r * E + e] - mx);
        float inv = 1.f / ssum;
        for (int e = 0; e < E; e++) {
            float wv = 0.f;
            if ((chosen >> e) & 1u) wv = expf(s_logits[r * E + e] - mx) * inv;
            out[(size_t)n * E + e] = wv;
        }
    }
}

extern "C" void kernel_launch(void* const* d_in, const int* in_sizes, int n_in,
                              void* d_out, int out_size, void* d_ws, size_t ws_size,
                              hipStream_t stream) {
    (void)n_in; (void)out_size;
    const float* tokens = (const float*)d_in[0];
    const float* encW1  = (const float*)d_in[1];
    const float* encB1  = (const float*)d_in[2];
    const float* encW2  = (const float*)d_in[3];
    const float* encB2  = (const float*)d_in[4];
    const float* specW1 = (const float*)d_in[5];
    const float* specB1 = (const float*)d_in[6];
    const float* specW2 = (const float*)d_in[7];
    // d_in[8] = spec_b2 (unused: softmax is shift-invariant)
    const float* defW1  = (const float*)d_in[9];
    const float* defB1  = (const float*)d_in[10];
    const float* defW2  = (const float*)d_in[11];
    const float* defB2  = (const float*)d_in[12];
    const int*   fiPtr  = (const int*)d_in[13];
    const int*   tkPtr  = (const int*)d_in[14];
    float* out = (float*)d_out;

    const int N = in_sizes[0] / (E * D);
    const int grid = (N + R - 1) / R;
    const bool useWs = (d_ws != nullptr) && (ws_size >= (size_t)(H * H * sizeof(float)));

    if (useWs) {
        wabc_prep<<<(H * H + 255) / 256, 256, 0, stream>>>(specW1, (float*)d_ws);
        router_kernel<true><<<grid, 256, 0, stream>>>(
            tokens, encW1, encB1, encW2, encB2, specW1, specB1, specW2,
            defW1, defB1, defW2, defB2, fiPtr, tkPtr, (const float*)d_ws, out, N);
    } else {
        router_kernel<false><<<grid, 256, 0, stream>>>(
            tokens, encW1, encB1, encW2, encB2, specW1, specB1, specW2,
            defW1, defB1, defW2, defB2, fiPtr, tkPtr, nullptr, out, N);
    }
}